// Round 5
// baseline (2504.321 us; speedup 1.0000x reference)
//
#include <hip/hip_runtime.h>
#include <math.h>

#define Bn 64
#define Tn 512
#define Dn 256
#define Hn 256
#define Gn 1024   // 4*H

// k_rec K-split per gate row (must sum to 256, chunk(8)-aligned):
#define KA 80     // k in [0,KA)            -> arch VGPRs   (KA/2 pairs * 4 rows = 2*KA regs)
#define KG 128    // k in [KA,KA+KG)        -> AGPRs        (2*KG regs = 256)
#define KLBASE (KA + KG)   // 208
#define KLCH ((256 - KLBASE) / 8)   // 6 LDS chunks per row

typedef _Float16 f16x2 __attribute__((ext_vector_type(2)));
typedef short bf16x8 __attribute__((ext_vector_type(8)));
typedef float f32x4 __attribute__((ext_vector_type(4)));

union U32H2 { unsigned int u; f16x2 h; };

__device__ __forceinline__ f16x2 u2h(unsigned int u) { U32H2 v; v.u = u; return v.h; }
__device__ __forceinline__ unsigned int packh2(float x, float y) {
    U32H2 v; v.h = (f16x2){(_Float16)x, (_Float16)y}; return v.u;
}

// fp32 -> bf16 round-to-nearest-even
__device__ __forceinline__ unsigned short f2bf(float x) {
    unsigned int u = __float_as_uint(x);
    u = u + 0x7FFFu + ((u >> 16) & 1u);
    return (unsigned short)(u >> 16);
}

#if __has_builtin(__builtin_amdgcn_fdot2)
__device__ __forceinline__ float fdot2f(f16x2 a, f16x2 b, float c) {
    return __builtin_amdgcn_fdot2(a, b, c, false);
}
#else
__device__ __forceinline__ float fdot2f(f16x2 a, f16x2 b, float c) {
    return fmaf((float)a[1], (float)b[1], fmaf((float)a[0], (float)b[0], c));
}
#endif

__device__ __forceinline__ float sigm(float x) {
    return __fdividef(1.0f, 1.0f + __expf(-x));
}
__device__ __forceinline__ float tanh_fast(float x) {
    float xc = fminf(fmaxf(x, -15.0f), 15.0f);
    float e = __expf(2.0f * xc);
    return 1.0f - __fdividef(2.0f, e + 1.0f);
}

// ---------------------------------------------------------------------------
// W_c[g][k] (bf16) = sum_d W_ih[g][d]*W_att[d][k];  bias_c[g] = W_ih[g]·b_att + b_ih[g] + b_hh[g]
// ---------------------------------------------------------------------------
__global__ void k_wc(const float* __restrict__ W_ih, const float* __restrict__ W_att,
                     const float* __restrict__ b_att, const float* __restrict__ b_ih,
                     const float* __restrict__ b_hh,
                     unsigned short* __restrict__ W_cb, float* __restrict__ bias_c) {
    int g = blockIdx.x;
    int k = threadIdx.x;
    __shared__ float wih_s[Dn];
    __shared__ float red[256];
    wih_s[k] = W_ih[g * Dn + k];
    __syncthreads();
    float acc = 0.0f;
    for (int d = 0; d < Dn; ++d)
        acc = fmaf(wih_s[d], W_att[d * Dn + k], acc);
    W_cb[g * Dn + k] = f2bf(acc);
    red[k] = wih_s[k] * b_att[k];
    __syncthreads();
    for (int s = 128; s > 0; s >>= 1) {
        if (k < s) red[k] += red[k + s];
        __syncthreads();
    }
    if (k == 0) bias_c[g] = red[0] + b_ih[g] + b_hh[g];
}

// ---------------------------------------------------------------------------
// vlin0[b][d] = values[b,0,:]·W_att[d,:] + b_att[d]
// ---------------------------------------------------------------------------
__global__ void k_vlin0(const float* __restrict__ values, const float* __restrict__ W_att,
                        const float* __restrict__ b_att, float* __restrict__ vlin0) {
    int b = blockIdx.x, d = threadIdx.x;
    __shared__ float v_s[Dn];
    v_s[d] = values[(size_t)b * Tn * Dn + d];
    __syncthreads();
    float acc = b_att[d];
    for (int k = 0; k < Dn; ++k)
        acc = fmaf(v_s[k], W_att[d * Dn + k], acc);
    vlin0[b * Dn + d] = acc;
}

// ---------------------------------------------------------------------------
// a_tj[b][t] = sigmoid( vlin0[b,:] · values[b,t,:] )
// ---------------------------------------------------------------------------
__global__ void k_atj(const float* __restrict__ values, const float* __restrict__ vlin0,
                      float* __restrict__ a_tj) {
    int wid = threadIdx.x >> 6, lane = threadIdx.x & 63;
    int idx = blockIdx.x * 4 + wid;            // b*T + t
    int b = idx >> 9;
    const float4* vp = (const float4*)(values + (size_t)idx * Dn);
    const float4* qp = (const float4*)(vlin0 + b * Dn);
    float4 v = vp[lane], q = qp[lane];
    float s = v.x * q.x + v.y * q.y + v.z * q.z + v.w * q.w;
    #pragma unroll
    for (int off = 32; off; off >>= 1) s += __shfl_xor(s, off);
    if (lane == 0) a_tj[idx] = 1.0f / (1.0f + expf(-s));
}

// ---------------------------------------------------------------------------
// xW = values(bf16) @ W_cb^T + bias_c ; M=32768, N=1024, K=256
// 128x128 tile, BK=32, 4 waves, mfma_f32_16x16x32_bf16
// ---------------------------------------------------------------------------
__global__ __launch_bounds__(256) void k_gemm(const float* __restrict__ A,
                                              const unsigned short* __restrict__ Bw,
                                              const float* __restrict__ bias,
                                              float* __restrict__ C) {
    __shared__ __align__(16) unsigned short As[128 * 32];
    __shared__ __align__(16) unsigned short Bs[128 * 32];
    const int tid = threadIdx.x;
    const int lane = tid & 63, wv = tid >> 6;
    const int wm = wv & 1, wn = wv >> 1;
    const int mBase = blockIdx.y * 128, nBase = blockIdx.x * 128;

    f32x4 acc[4][4];
    #pragma unroll
    for (int i = 0; i < 4; ++i)
        #pragma unroll
        for (int jj = 0; jj < 4; ++jj)
            acc[i][jj] = (f32x4){0.f, 0.f, 0.f, 0.f};

    for (int kb = 0; kb < 256; kb += 32) {
        #pragma unroll
        for (int p = 0; p < 2; ++p) {
            int idx = p * 256 + tid;
            int r = idx >> 2, c = idx & 3;
            const float* src = A + (size_t)(mBase + r) * 256 + kb + c * 8;
            float4 f0 = *(const float4*)src;
            float4 f1 = *(const float4*)(src + 4);
            bf16x8 v;
            v[0] = (short)f2bf(f0.x); v[1] = (short)f2bf(f0.y);
            v[2] = (short)f2bf(f0.z); v[3] = (short)f2bf(f0.w);
            v[4] = (short)f2bf(f1.x); v[5] = (short)f2bf(f1.y);
            v[6] = (short)f2bf(f1.z); v[7] = (short)f2bf(f1.w);
            int cs = c ^ ((r >> 1) & 3);
            *(bf16x8*)&As[r * 32 + cs * 8] = v;
        }
        #pragma unroll
        for (int p = 0; p < 2; ++p) {
            int idx = p * 256 + tid;
            int r = idx >> 2, c = idx & 3;
            bf16x8 v = *(const bf16x8*)(Bw + (size_t)(nBase + r) * 256 + kb + c * 8);
            int cs = c ^ ((r >> 1) & 3);
            *(bf16x8*)&Bs[r * 32 + cs * 8] = v;
        }
        __syncthreads();

        bf16x8 af[4], bfr[4];
        #pragma unroll
        for (int f = 0; f < 4; ++f) {
            int ra = wm * 64 + f * 16 + (lane & 15);
            int ca = (lane >> 4) ^ ((ra >> 1) & 3);
            af[f] = *(const bf16x8*)&As[ra * 32 + ca * 8];
            int rb = wn * 64 + f * 16 + (lane & 15);
            int cb = (lane >> 4) ^ ((rb >> 1) & 3);
            bfr[f] = *(const bf16x8*)&Bs[rb * 32 + cb * 8];
        }
        #pragma unroll
        for (int fm = 0; fm < 4; ++fm)
            #pragma unroll
            for (int fn = 0; fn < 4; ++fn)
                acc[fm][fn] = __builtin_amdgcn_mfma_f32_16x16x32_bf16(af[fm], bfr[fn], acc[fm][fn], 0, 0, 0);
        __syncthreads();
    }
    #pragma unroll
    for (int fm = 0; fm < 4; ++fm) {
        #pragma unroll
        for (int fn = 0; fn < 4; ++fn) {
            #pragma unroll
            for (int r = 0; r < 4; ++r) {
                int row = mBase + wm * 64 + fm * 16 + (lane >> 4) * 4 + r;
                int col = nBase + wn * 64 + fn * 16 + (lane & 15);
                C[(size_t)row * Gn + col] = acc[fm][fn][r] + bias[col];
            }
        }
    }
}

// ---------------------------------------------------------------------------
// Recurrence v5: 1 WG (256 thr, 4 waves, 1 wave/SIMD) per batch.
// waves_per_eu(1,1) -> 256 ArchVGPR + 256 AGPR budget per wave (full 512-reg
// unified pool at 4 waves/CU). Thread j owns unit j's 4 gate rows {j,j+256,
// j+512,j+768} -> gates fully thread-local, no shfl.
// W_hh f16 split per row: k<80 arch VGPRs (160 regs), k in [80,208) AGPRs
// (256 regs, pinned via asm "+a"), k in [208,256) LDS chunk-major (96 KB,
// stride-1 b128). h double-buffered f16 in LDS; one lgkm-only barrier/step.
// ---------------------------------------------------------------------------
__global__ __attribute__((amdgpu_flat_work_group_size(256, 256), amdgpu_waves_per_eu(1, 1)))
void k_rec(const float* __restrict__ xW,      // [B,T,1024] (all biases folded)
           const float* __restrict__ W_hh,    // [1024,256]
           const float* __restrict__ Deltas,  // [B,T,256]
           const float* __restrict__ a_tj,    // [B,T]
           float* __restrict__ out) {         // [B,T,256]
    extern __shared__ __align__(16) char smem[];
    uint4*    Wl4  = (uint4*)smem;                         // [KLCH][1024] = 96 KB
    _Float16* hbuf = (_Float16*)(smem + KLCH * 1024 * 16); // [2][256] = 1 KB

    const int j = threadIdx.x;
    const int b = blockIdx.x;

    // ---- arch-VGPR weights: k in [0,KA), rows j+256i ----
    f16x2 wv[4][KA / 2];
    // ---- AGPR weights: k in [KA,KA+KG) as packed u32 pairs ----
    unsigned wg[4][KG / 2];
    #pragma unroll
    for (int i = 0; i < 4; ++i) {
        const float2* p2 = (const float2*)(W_hh + (size_t)(j + 256 * i) * 256);
        #pragma unroll
        for (int q = 0; q < KA / 2; ++q) {
            float2 v = p2[q];
            wv[i][q] = (f16x2){(_Float16)v.x, (_Float16)v.y};
        }
        #pragma unroll
        for (int q = 0; q < KG / 2; ++q) {
            float2 v = p2[KA / 2 + q];
            unsigned pk = packh2(v.x, v.y);
            asm volatile("" : "+a"(pk));   // pin into AGPR class at definition
            wg[i][q] = pk;
        }
    }
    // ---- LDS weights: k in [KLBASE,256), chunk-major Wl4[c][row] ----
    for (int idx = j; idx < KLCH * 1024; idx += 256) {
        int c = idx >> 10, r = idx & 1023;
        const float* src = W_hh + (size_t)r * 256 + KLBASE + c * 8;
        float4 f0 = *(const float4*)src;
        float4 f1 = *(const float4*)(src + 4);
        Wl4[c * 1024 + r] = (uint4){ packh2(f0.x, f0.y), packh2(f0.z, f0.w),
                                     packh2(f1.x, f1.y), packh2(f1.z, f1.w) };
    }

    float cst = 0.0f, c0, dcrun;

    // ---- t = 0: gates from xW only (h=0); carry c stays 0, c_0 kept ----
    {
        size_t xb = (size_t)b * Tn * Gn;
        float gi = xW[xb + j];
        float gg = xW[xb + 512 + j];
        float go = xW[xb + 768 + j];
        dcrun = Deltas[(size_t)b * Tn * Dn + j];
        c0 = sigm(gi) * tanh_fast(gg);
        float h = sigm(go) * tanh_fast(c0);
        out[(size_t)b * Tn * Hn + j] = h;
        hbuf[j] = (_Float16)h;
    }
    __syncthreads();

    // ---- main loop t = 1..511 ----
    #pragma unroll 1
    for (int t = 1; t < Tn; ++t) {
        size_t xb = ((size_t)b * Tn + t) * Gn;
        float xw0 = xW[xb + j];
        float xw1 = xW[xb + 256 + j];
        float xw2 = xW[xb + 512 + j];
        float xw3 = xW[xb + 768 + j];
        float del = Deltas[((size_t)b * Tn + t) * Dn + j];
        float at  = a_tj[b * Tn + t];

        const uint4* hp = (const uint4*)(hbuf + ((t + 1) & 1) * 256);
        float s0[4] = {0.f, 0.f, 0.f, 0.f};
        float s1[4] = {0.f, 0.f, 0.f, 0.f};

        // LDS-weight section: chunks [KLBASE/8, 32)
        #pragma unroll
        for (int c = 0; c < KLCH; ++c) {
            uint4 hv = hp[KLBASE / 8 + c];
            #pragma unroll
            for (int i = 0; i < 4; ++i) {
                uint4 w = Wl4[c * 1024 + j + 256 * i];
                s0[i] = fdot2f(u2h(w.x), u2h(hv.x), s0[i]);
                s1[i] = fdot2f(u2h(w.y), u2h(hv.y), s1[i]);
                s0[i] = fdot2f(u2h(w.z), u2h(hv.z), s0[i]);
                s1[i] = fdot2f(u2h(w.w), u2h(hv.w), s1[i]);
            }
        }
        // arch-VGPR section: chunks [0, KA/8)
        #pragma unroll
        for (int c = 0; c < KA / 8; ++c) {
            uint4 hv = hp[c];
            f16x2 h0 = u2h(hv.x), h1 = u2h(hv.y), h2 = u2h(hv.z), h3 = u2h(hv.w);
            #pragma unroll
            for (int i = 0; i < 4; ++i) {
                s0[i] = fdot2f(wv[i][c * 4 + 0], h0, s0[i]);
                s1[i] = fdot2f(wv[i][c * 4 + 1], h1, s1[i]);
                s0[i] = fdot2f(wv[i][c * 4 + 2], h2, s0[i]);
                s1[i] = fdot2f(wv[i][c * 4 + 3], h3, s1[i]);
            }
        }
        // AGPR section: chunks [KA/8, KLBASE/8)
        #pragma unroll
        for (int c = 0; c < KG / 8; ++c) {
            uint4 hv = hp[KA / 8 + c];
            f16x2 h0 = u2h(hv.x), h1 = u2h(hv.y), h2 = u2h(hv.z), h3 = u2h(hv.w);
            #pragma unroll
            for (int i = 0; i < 4; ++i) {
                s0[i] = fdot2f(u2h(wg[i][c * 4 + 0]), h0, s0[i]);
                s1[i] = fdot2f(u2h(wg[i][c * 4 + 1]), h1, s1[i]);
                s0[i] = fdot2f(u2h(wg[i][c * 4 + 2]), h2, s0[i]);
                s1[i] = fdot2f(u2h(wg[i][c * 4 + 3]), h3, s1[i]);
            }
        }

        float gi = xw0 + s0[0] + s1[0];
        float gf = xw1 + s0[1] + s1[1];
        float gg = xw2 + s0[2] + s1[2];
        float go = xw3 + s0[3] + s1[3];

        dcrun += del;
        float alpha = __fdividef(at, __logf(2.718281828459045f + dcrun));
        float cmix = alpha * c0 + (1.0f - alpha) * cst;
        cst = sigm(gf) * cmix + sigm(gi) * tanh_fast(gg);
        float h = sigm(go) * tanh_fast(cst);

        out[((size_t)b * Tn + t) * Hn + j] = h;
        hbuf[(t & 1) * 256 + j] = (_Float16)h;

        // raw barrier: drain LDS writes only (no vmcnt drain of the out-store)
        asm volatile("s_waitcnt lgkmcnt(0)" ::: "memory");
        __builtin_amdgcn_s_barrier();
        __builtin_amdgcn_sched_barrier(0);
    }

    // anchor AGPR live ranges at kernel end (keeps interior in AGPR class)
    #pragma unroll
    for (int i = 0; i < 4; ++i)
        #pragma unroll
        for (int q = 0; q < KG / 2; ++q)
            asm volatile("" :: "a"(wg[i][q]));
}

// ---------------------------------------------------------------------------
extern "C" void kernel_launch(void* const* d_in, const int* in_sizes, int n_in,
                              void* d_out, int out_size, void* d_ws, size_t ws_size,
                              hipStream_t stream) {
    const float* values = (const float*)d_in[0];
    const float* Deltas = (const float*)d_in[1];
    const float* W_att  = (const float*)d_in[2];
    const float* b_att  = (const float*)d_in[3];
    const float* W_ih   = (const float*)d_in[4];
    const float* W_hh   = (const float*)d_in[5];
    const float* b_ih   = (const float*)d_in[6];
    const float* b_hh   = (const float*)d_in[7];
    float* out = (float*)d_out;

    float* xW = (float*)d_ws;                                   // 33,554,432 f
    unsigned short* W_cb = (unsigned short*)(xW + (size_t)32768 * 1024);
    float* bias_c = (float*)(W_cb + 1024 * 256);
    float* vlin0  = bias_c + 1024;
    float* atj    = vlin0 + 64 * 256;

    k_wc<<<1024, 256, 0, stream>>>(W_ih, W_att, b_att, b_ih, b_hh, W_cb, bias_c);
    k_vlin0<<<64, 256, 0, stream>>>(values, W_att, b_att, vlin0);
    k_atj<<<8192, 256, 0, stream>>>(values, vlin0, atj);
    k_gemm<<<dim3(8, 256), 256, 0, stream>>>(values, W_cb, bias_c, xW);
    k_rec<<<64, 256, KLCH * 1024 * 16 + 1024, stream>>>(xW, W_hh, Deltas, atj, out);
}

// Round 6
// 1068.265 us; speedup vs baseline: 2.3443x; 2.3443x over previous
//
#include <hip/hip_runtime.h>
#include <math.h>

#define Bn 64
#define Tn 512
#define Dn 256
#define Hn 256
#define Gn 1024   // 4*H

typedef _Float16 f16x2 __attribute__((ext_vector_type(2)));
typedef short bf16x8 __attribute__((ext_vector_type(8)));
typedef float f32x4 __attribute__((ext_vector_type(4)));

union U32H2 { unsigned int u; f16x2 h; };

__device__ __forceinline__ f16x2 u2h(unsigned int u) { U32H2 v; v.u = u; return v.h; }
__device__ __forceinline__ unsigned int packh2(float x, float y) {
    U32H2 v; v.h = (f16x2){(_Float16)x, (_Float16)y}; return v.u;
}

// fp32 -> bf16 round-to-nearest-even
__device__ __forceinline__ unsigned short f2bf(float x) {
    unsigned int u = __float_as_uint(x);
    u = u + 0x7FFFu + ((u >> 16) & 1u);
    return (unsigned short)(u >> 16);
}

#if __has_builtin(__builtin_amdgcn_fdot2)
__device__ __forceinline__ float fdot2f(f16x2 a, f16x2 b, float c) {
    return __builtin_amdgcn_fdot2(a, b, c, false);
}
#else
__device__ __forceinline__ float fdot2f(f16x2 a, f16x2 b, float c) {
    return fmaf((float)a[1], (float)b[1], fmaf((float)a[0], (float)b[0], c));
}
#endif

__device__ __forceinline__ float sigm(float x) {
    return __fdividef(1.0f, 1.0f + __expf(-x));
}
__device__ __forceinline__ float tanh_fast(float x) {
    float xc = fminf(fmaxf(x, -15.0f), 15.0f);
    float e = __expf(2.0f * xc);
    return 1.0f - __fdividef(2.0f, e + 1.0f);
}

// ---------------------------------------------------------------------------
// W_c[g][k] (bf16) = sum_d W_ih[g][d]*W_att[d][k];  bias_c[g] = W_ih[g]·b_att + b_ih[g] + b_hh[g]
// ---------------------------------------------------------------------------
__global__ void k_wc(const float* __restrict__ W_ih, const float* __restrict__ W_att,
                     const float* __restrict__ b_att, const float* __restrict__ b_ih,
                     const float* __restrict__ b_hh,
                     unsigned short* __restrict__ W_cb, float* __restrict__ bias_c) {
    int g = blockIdx.x;
    int k = threadIdx.x;
    __shared__ float wih_s[Dn];
    __shared__ float red[256];
    wih_s[k] = W_ih[g * Dn + k];
    __syncthreads();
    float acc = 0.0f;
    for (int d = 0; d < Dn; ++d)
        acc = fmaf(wih_s[d], W_att[d * Dn + k], acc);
    W_cb[g * Dn + k] = f2bf(acc);
    red[k] = wih_s[k] * b_att[k];
    __syncthreads();
    for (int s = 128; s > 0; s >>= 1) {
        if (k < s) red[k] += red[k + s];
        __syncthreads();
    }
    if (k == 0) bias_c[g] = red[0] + b_ih[g] + b_hh[g];
}

// ---------------------------------------------------------------------------
// vlin0[b][d] = values[b,0,:]·W_att[d,:] + b_att[d]
// ---------------------------------------------------------------------------
__global__ void k_vlin0(const float* __restrict__ values, const float* __restrict__ W_att,
                        const float* __restrict__ b_att, float* __restrict__ vlin0) {
    int b = blockIdx.x, d = threadIdx.x;
    __shared__ float v_s[Dn];
    v_s[d] = values[(size_t)b * Tn * Dn + d];
    __syncthreads();
    float acc = b_att[d];
    for (int k = 0; k < Dn; ++k)
        acc = fmaf(v_s[k], W_att[d * Dn + k], acc);
    vlin0[b * Dn + d] = acc;
}

// ---------------------------------------------------------------------------
// a_tj[b][t] = sigmoid( vlin0[b,:] · values[b,t,:] )
// ---------------------------------------------------------------------------
__global__ void k_atj(const float* __restrict__ values, const float* __restrict__ vlin0,
                      float* __restrict__ a_tj) {
    int wid = threadIdx.x >> 6, lane = threadIdx.x & 63;
    int idx = blockIdx.x * 4 + wid;            // b*T + t
    int b = idx >> 9;
    const float4* vp = (const float4*)(values + (size_t)idx * Dn);
    const float4* qp = (const float4*)(vlin0 + b * Dn);
    float4 v = vp[lane], q = qp[lane];
    float s = v.x * q.x + v.y * q.y + v.z * q.z + v.w * q.w;
    #pragma unroll
    for (int off = 32; off; off >>= 1) s += __shfl_xor(s, off);
    if (lane == 0) a_tj[idx] = 1.0f / (1.0f + expf(-s));
}

// ---------------------------------------------------------------------------
// xW = values(bf16) @ W_cb^T + bias_c ; M=32768, N=1024, K=256
// 128x128 tile, BK=32, 4 waves, mfma_f32_16x16x32_bf16
// ---------------------------------------------------------------------------
__global__ __launch_bounds__(256) void k_gemm(const float* __restrict__ A,
                                              const unsigned short* __restrict__ Bw,
                                              const float* __restrict__ bias,
                                              float* __restrict__ C) {
    __shared__ __align__(16) unsigned short As[128 * 32];
    __shared__ __align__(16) unsigned short Bs[128 * 32];
    const int tid = threadIdx.x;
    const int lane = tid & 63, wv = tid >> 6;
    const int wm = wv & 1, wn = wv >> 1;
    const int mBase = blockIdx.y * 128, nBase = blockIdx.x * 128;

    f32x4 acc[4][4];
    #pragma unroll
    for (int i = 0; i < 4; ++i)
        #pragma unroll
        for (int jj = 0; jj < 4; ++jj)
            acc[i][jj] = (f32x4){0.f, 0.f, 0.f, 0.f};

    for (int kb = 0; kb < 256; kb += 32) {
        #pragma unroll
        for (int p = 0; p < 2; ++p) {
            int idx = p * 256 + tid;
            int r = idx >> 2, c = idx & 3;
            const float* src = A + (size_t)(mBase + r) * 256 + kb + c * 8;
            float4 f0 = *(const float4*)src;
            float4 f1 = *(const float4*)(src + 4);
            bf16x8 v;
            v[0] = (short)f2bf(f0.x); v[1] = (short)f2bf(f0.y);
            v[2] = (short)f2bf(f0.z); v[3] = (short)f2bf(f0.w);
            v[4] = (short)f2bf(f1.x); v[5] = (short)f2bf(f1.y);
            v[6] = (short)f2bf(f1.z); v[7] = (short)f2bf(f1.w);
            int cs = c ^ ((r >> 1) & 3);
            *(bf16x8*)&As[r * 32 + cs * 8] = v;
        }
        #pragma unroll
        for (int p = 0; p < 2; ++p) {
            int idx = p * 256 + tid;
            int r = idx >> 2, c = idx & 3;
            bf16x8 v = *(const bf16x8*)(Bw + (size_t)(nBase + r) * 256 + kb + c * 8);
            int cs = c ^ ((r >> 1) & 3);
            *(bf16x8*)&Bs[r * 32 + cs * 8] = v;
        }
        __syncthreads();

        bf16x8 af[4], bfr[4];
        #pragma unroll
        for (int f = 0; f < 4; ++f) {
            int ra = wm * 64 + f * 16 + (lane & 15);
            int ca = (lane >> 4) ^ ((ra >> 1) & 3);
            af[f] = *(const bf16x8*)&As[ra * 32 + ca * 8];
            int rb = wn * 64 + f * 16 + (lane & 15);
            int cb = (lane >> 4) ^ ((rb >> 1) & 3);
            bfr[f] = *(const bf16x8*)&Bs[rb * 32 + cb * 8];
        }
        #pragma unroll
        for (int fm = 0; fm < 4; ++fm)
            #pragma unroll
            for (int fn = 0; fn < 4; ++fn)
                acc[fm][fn] = __builtin_amdgcn_mfma_f32_16x16x32_bf16(af[fm], bfr[fn], acc[fm][fn], 0, 0, 0);
        __syncthreads();
    }
    #pragma unroll
    for (int fm = 0; fm < 4; ++fm) {
        #pragma unroll
        for (int fn = 0; fn < 4; ++fn) {
            #pragma unroll
            for (int r = 0; r < 4; ++r) {
                int row = mBase + wm * 64 + fm * 16 + (lane >> 4) * 4 + r;
                int col = nBase + wn * 64 + fn * 16 + (lane & 15);
                C[(size_t)row * Gn + col] = acc[fm][fn][r] + bias[col];
            }
        }
    }
}

// ---------------------------------------------------------------------------
// Recurrence v6: 4 WGs per batch (256 WGs, 1/CU). WG w: xcd=w&7, q=(w>>3)&3,
// g=w>>5, batch b = xcd*8+g (partner WGs share the XCD under round-robin
// dispatch). WG owns units [q*64, q*64+64) -> 256 gate rows; 512 threads,
// lane l = vv*8 + gate*2 + khalf: thread holds W_hh[gate*256+u][khalf*128..+128)
// entirely in 64 f16x2 VGPRs (no LDS weights, no spill at the 128-reg budget).
// khalf-reduce + 4-gate gather via 5 intra-wave shfl_xor; h computed
// redundantly per unit's 8 lanes. Cross-WG h exchange: tagged u64
// {tag=t+1 | 2xf16} relaxed agent atomics — the tag is the flag; one
// __syncthreads per step. Handshake provides all cross-step ordering.
// xW/Deltas/a_tj prefetched one step ahead (in flight during the spin).
// ---------------------------------------------------------------------------
__global__ __launch_bounds__(512, 2)
void k_rec(const float* __restrict__ xW,      // [B,T,1024] (all biases folded)
           const float* __restrict__ W_hh,    // [1024,256]
           const float* __restrict__ Deltas,  // [B,T,256]
           const float* __restrict__ a_tj,    // [B,T]
           unsigned long long* __restrict__ hglob, // [B][2][128] {tag|h-pair}
           float* __restrict__ out) {         // [B,T,256]
    extern __shared__ __align__(16) char smem[];
    unsigned* hbuf = (unsigned*)smem;          // [2][128] u32 (f16 pairs)

    const int tid = threadIdx.x;
    const int w = blockIdx.x;
    const int q = (w >> 3) & 3;
    const int b = (w & 7) * 8 + (w >> 5);
    const int l = tid & 63;
    const int Wv = tid >> 6;
    const int vv = l >> 3;
    const int gate = (l >> 1) & 3;
    const int khalf = l & 1;
    const int u = q * 64 + Wv * 8 + vv;        // unit in [q*64, q*64+64)
    const int R = gate * 256 + u;              // gate row

    // ---- weights: half-row in 64 f16x2 VGPRs ----
    f16x2 wreg[64];
    {
        const float4* wp = (const float4*)(W_hh + (size_t)R * 256 + khalf * 128);
        #pragma unroll
        for (int i = 0; i < 32; ++i) {
            float4 v = wp[i];
            wreg[2 * i]     = (f16x2){(_Float16)v.x, (_Float16)v.y};
            wreg[2 * i + 1] = (f16x2){(_Float16)v.z, (_Float16)v.w};
        }
    }

    const size_t xrow = (size_t)b * Tn;
    float cst = 0.0f, c0, dcrun;
    float xw, del, at;

    // ---- t = 0: gates from xW only (h=0); carry c stays 0, c_0 kept ----
    {
        xw  = xW[xrow * Gn + R];
        del = Deltas[xrow * Dn + u];
        float Sr = xw;
        float g2 = __shfl_xor(Sr, 2);
        float p0 = (gate & 1) ? g2 : Sr;
        float p1 = (gate & 1) ? Sr : g2;
        float q0 = __shfl_xor(p0, 4);
        float q1 = __shfl_xor(p1, 4);
        float gi = (gate < 2) ? p0 : q0;
        float gg = (gate < 2) ? q0 : p0;
        float go = (gate < 2) ? q1 : p1;
        dcrun = del;
        c0 = sigm(gi) * tanh_fast(gg);
        float h = sigm(go) * tanh_fast(c0);
        float hn = __shfl_xor(h, 8);
        unsigned hpk = packh2(h, hn);
        if ((l & 15) == 0) {
            hbuf[u >> 1] = hpk;                                  // buffer 0
            unsigned long long pv = (1ull << 32) | (unsigned long long)hpk;
            __hip_atomic_store(&hglob[((size_t)b * 2 + 0) * 128 + (u >> 1)], pv,
                               __ATOMIC_RELAXED, __HIP_MEMORY_SCOPE_AGENT);
        }
        if ((l & 7) == 0) out[xrow * Hn + u] = h;
        // prefetch t = 1
        xw  = xW[(xrow + 1) * Gn + R];
        del = Deltas[(xrow + 1) * Dn + u];
        at  = a_tj[xrow + 1];
    }

    // ---- main loop t = 1..511 ----
    #pragma unroll 1
    for (int t = 1; t < Tn; ++t) {
        const int rb = (t - 1) & 1;
        // prefetch t+1 (in flight during spin)
        const int tn = (t + 1 < Tn) ? (t + 1) : t;
        float xw_n  = xW[(xrow + tn) * Gn + R];
        float del_n = Deltas[(xrow + tn) * Dn + u];
        float at_n  = a_tj[xrow + tn];

        // fill partner h (tag == t means partner finished step t-1)
        if (tid < 96) {
            const int pi = tid >> 5, off = tid & 31;
            const int qp = pi + (pi >= q ? 1 : 0);
            const unsigned long long* src =
                &hglob[((size_t)b * 2 + rb) * 128 + qp * 32 + off];
            unsigned long long v;
            for (;;) {
                v = __hip_atomic_load(src, __ATOMIC_RELAXED, __HIP_MEMORY_SCOPE_AGENT);
                if ((unsigned)(v >> 32) == (unsigned)t) break;
                __builtin_amdgcn_s_sleep(1);
            }
            hbuf[rb * 128 + qp * 32 + off] = (unsigned)v;
        }
        __syncthreads();

        // half-row dot over h_{t-1}
        float s0 = 0.f, s1 = 0.f;
        const uint4* hp = (const uint4*)(hbuf + rb * 128 + khalf * 64);
        #pragma unroll
        for (int cc = 0; cc < 16; ++cc) {
            uint4 hv = hp[cc];
            s0 = fdot2f(wreg[cc * 4 + 0], u2h(hv.x), s0);
            s1 = fdot2f(wreg[cc * 4 + 1], u2h(hv.y), s1);
            s0 = fdot2f(wreg[cc * 4 + 2], u2h(hv.z), s0);
            s1 = fdot2f(wreg[cc * 4 + 3], u2h(hv.w), s1);
        }
        float Sr = s0 + s1;
        Sr += __shfl_xor(Sr, 1);     // combine k-halves
        Sr += xw;
        float g2 = __shfl_xor(Sr, 2);
        float p0 = (gate & 1) ? g2 : Sr;
        float p1 = (gate & 1) ? Sr : g2;
        float q0 = __shfl_xor(p0, 4);
        float q1 = __shfl_xor(p1, 4);
        float gi = (gate < 2) ? p0 : q0;
        float gf = (gate < 2) ? p1 : q1;
        float gg = (gate < 2) ? q0 : p0;
        float go = (gate < 2) ? q1 : p1;

        dcrun += del;
        float alpha = __fdividef(at, __logf(2.718281828459045f + dcrun));
        float cmix = alpha * c0 + (1.0f - alpha) * cst;
        cst = sigm(gf) * cmix + sigm(gi) * tanh_fast(gg);
        float h = sigm(go) * tanh_fast(cst);

        float hn = __shfl_xor(h, 8);
        unsigned hpk = packh2(h, hn);
        if ((l & 15) == 0) {
            hbuf[(t & 1) * 128 + (u >> 1)] = hpk;
            unsigned long long pv =
                ((unsigned long long)(unsigned)(t + 1) << 32) | (unsigned long long)hpk;
            __hip_atomic_store(&hglob[((size_t)b * 2 + (t & 1)) * 128 + (u >> 1)], pv,
                               __ATOMIC_RELAXED, __HIP_MEMORY_SCOPE_AGENT);
        }
        if ((l & 7) == 0) out[(xrow + t) * Hn + u] = h;

        xw = xw_n; del = del_n; at = at_n;
    }
}

// ---------------------------------------------------------------------------
extern "C" void kernel_launch(void* const* d_in, const int* in_sizes, int n_in,
                              void* d_out, int out_size, void* d_ws, size_t ws_size,
                              hipStream_t stream) {
    const float* values = (const float*)d_in[0];
    const float* Deltas = (const float*)d_in[1];
    const float* W_att  = (const float*)d_in[2];
    const float* b_att  = (const float*)d_in[3];
    const float* W_ih   = (const float*)d_in[4];
    const float* W_hh   = (const float*)d_in[5];
    const float* b_ih   = (const float*)d_in[6];
    const float* b_hh   = (const float*)d_in[7];
    float* out = (float*)d_out;

    char* wsb = (char*)d_ws;
    float* xW            = (float*)(wsb);                       // 134,217,728 B
    unsigned short* W_cb = (unsigned short*)(wsb + 134217728);  //     524,288 B
    float* bias_c        = (float*)(wsb + 134742016);           //       4,096 B
    float* vlin0         = (float*)(wsb + 134746112);           //      65,536 B
    float* atj           = (float*)(wsb + 134811648);           //     131,072 B
    unsigned long long* hglob = (unsigned long long*)(wsb + 134942720); // 131,072 B

    k_wc<<<1024, 256, 0, stream>>>(W_ih, W_att, b_att, b_ih, b_hh, W_cb, bias_c);
    k_vlin0<<<64, 256, 0, stream>>>(values, W_att, b_att, vlin0);
    k_atj<<<8192, 256, 0, stream>>>(values, vlin0, atj);
    k_gemm<<<dim3(8, 256), 256, 0, stream>>>(values, W_cb, bias_c, xW);
    k_rec<<<256, 512, 81920, stream>>>(xW, W_hh, Deltas, atj, hglob, out);
}